// Round 1
// baseline (290.263 us; speedup 1.0000x reference)
//
#include <hip/hip_runtime.h>
#include <hip/hip_bf16.h>

// ---------------------------------------------------------------------------
// BF_NIR_conv: feat [1,128,128,128], lr_guide [1,128,128,128],
// hr_guide [1,128,256,256], MLP 386->256->128->32, 4-branch nearest-sample
// ensemble with softmax weights. Output [1,32,256,256] fp32.
//
// Decomposition:
//   U[pos][256]  = featc[:,pos] @ W1[0:256,:]          (16384 LR positions)
//   G[p][256]    = hr_guide[:,p] @ W1[256:384,:] + b1  (65536 HR pixels)
//   h1 = relu(U[spos] + G[p] + rel_y*W1[384] + rel_x*W1[385])
//   h2 = relu(h1 @ W2 + b2);  pred = h2 @ W3 + b3
//   out[p] = sum_k softmax(gc)_k * pred_k
// ---------------------------------------------------------------------------

using bf16x8 = __attribute__((ext_vector_type(8))) __bf16;
using f32x4  = __attribute__((ext_vector_type(4))) float;

__device__ __forceinline__ float bf2f(unsigned short u){
  unsigned int x = ((unsigned int)u) << 16;
  return __builtin_bit_cast(float, x);
}
__device__ __forceinline__ unsigned short f2bf(float f){
  unsigned int x = __builtin_bit_cast(unsigned int, f);
  unsigned int r = x + 0x7fffu + ((x >> 16) & 1u);
  return (unsigned short)(r >> 16);
}
__device__ __forceinline__ bf16x8 ld8(const ushort* p){
  uint4 r = *(const uint4*)p;
  return __builtin_bit_cast(bf16x8, r);
}

// --- kernel 0: convert weights to bf16, transposed to [N][K] so B fragments
// (8 consecutive K at fixed N) are single 16B loads ---------------------------
__global__ __launch_bounds__(256) void convert_weights(
    const float* __restrict__ W1, const float* __restrict__ W2,
    const float* __restrict__ W3,
    ushort* __restrict__ W1t,   // [256][384]
    ushort* __restrict__ W2t,   // [128][256]
    ushort* __restrict__ W3t)   // [32][128]
{
  int i = blockIdx.x*256 + threadIdx.x;           // grid = 384 blocks -> i < 98304
  { int k = i >> 8, n = i & 255; W1t[n*384 + k] = f2bf(W1[i]); }
  if (i < 32768){ int k = i >> 7, n = i & 127; W2t[n*256 + k] = f2bf(W2[i]); }
  if (i < 4096) { int k = i >> 5, n = i & 31;  W3t[n*128 + k] = f2bf(W3[i]); }
}

// --- kernels 1&2: stage-1 GEMM: out[pos][n] = sum_k src[k][pos]*W1[koff+k][n]
// src is channel-major [K][M]. K = 128 per half (2 halves when src1 != null).
// Block: 256 thr / 4 waves, M-tile 64, N = 256 (wave owns 64 cols). ----------
__global__ __launch_bounds__(256) void stage1_gemm(
    const float* __restrict__ src0, const float* __restrict__ src1, int M,
    const ushort* __restrict__ Bt, int koff,   // W1t [256][384]
    const float* __restrict__ bias,
    ushort* __restrict__ outp)                 // [M][256]
{
  __shared__ ushort A[64*136];                 // 64 pos x 128 chan, +8 pad
  const int t = threadIdx.x;
  const int w = t >> 6, lane = t & 63, quad = lane >> 4, l15 = lane & 15;
  const int pos0 = blockIdx.x * 64;
  const int nhalf = src1 ? 2 : 1;

  f32x4 acc[4][4];
  #pragma unroll
  for (int mt=0; mt<4; mt++)
    #pragma unroll
    for (int nt=0; nt<4; nt++) acc[mt][nt] = f32x4{0.f,0.f,0.f,0.f};

  for (int h=0; h<nhalf; h++){
    const float* src = h ? src1 : src0;
    #pragma unroll
    for (int i=0; i<32; i++){                  // coalesced stage + transpose
      int f = i*256 + t;
      int k = f >> 6, m = f & 63;
      A[m*136 + k] = f2bf(src[(size_t)k*M + pos0 + m]);
    }
    __syncthreads();
    bf16x8 b[4][4];
    #pragma unroll
    for (int kt=0; kt<4; kt++)
      #pragma unroll
      for (int nt=0; nt<4; nt++)
        b[kt][nt] = ld8(&Bt[(size_t)(w*64 + nt*16 + l15)*384 + koff + h*128 + kt*32 + quad*8]);
    #pragma unroll
    for (int mt=0; mt<4; mt++)
      #pragma unroll
      for (int kt=0; kt<4; kt++){
        bf16x8 a = ld8(&A[(mt*16 + l15)*136 + kt*32 + quad*8]);
        #pragma unroll
        for (int nt=0; nt<4; nt++)
          acc[mt][nt] = __builtin_amdgcn_mfma_f32_16x16x32_bf16(a, b[kt][nt], acc[mt][nt], 0,0,0);
      }
    __syncthreads();
  }
  #pragma unroll
  for (int mt=0; mt<4; mt++)
    #pragma unroll
    for (int nt=0; nt<4; nt++){
      int n = w*64 + nt*16 + l15;
      float bv = bias ? bias[n] : 0.0f;
      #pragma unroll
      for (int r=0; r<4; r++){
        int m = mt*16 + quad*4 + r;            // C/D: row = quad*4+reg, col = l15
        outp[(size_t)(pos0 + m)*256 + n] = f2bf(acc[mt][nt][r] + bv);
      }
    }
}

// --- kernel 3: main. Block = 16 HR pixels (4x4 tile) x 4 branches = 64 rows.
__global__ __launch_bounds__(256) void main_kernel(
    const float* __restrict__ feat,   // [128][16384]
    const float* __restrict__ W1,     // [386][256] fp32 (rel rows 384/385)
    const float* __restrict__ b2v,    // [128]
    const float* __restrict__ b3v,    // [32]
    const ushort* __restrict__ U,     // [16384][256] bf16
    const ushort* __restrict__ G,     // [65536][256] bf16 (b1 folded)
    const ushort* __restrict__ W2t,   // [128][256] bf16 (N-major)
    const ushort* __restrict__ W3t,   // [32][128]  bf16 (N-major)
    float* __restrict__ outp)         // [32][65536]
{
  __shared__ ushort A1[64*264];       // h1: 64 rows x 256, +8 pad
  __shared__ ushort A2[64*136];       // h2: 64 rows x 128, +8 pad
  __shared__ int   rowpos[64];
  __shared__ float rowrely[64], rowrelx[64];
  __shared__ float gcs[64];
  __shared__ float wgt[64];           // [pix][branch] softmax weights

  const int t = threadIdx.x;
  const int w = t >> 6, lane = t & 63, quad = lane >> 4, l15 = lane & 15;
  const int bY = (blockIdx.x >> 6) * 4;
  const int bX = (blockIdx.x & 63) * 4;

  // ---- step A: per-row sample metadata + gc dot products
  if (t < 64){
    int r = t;
    int lp = r >> 2, k = r & 3;
    int Y = bY + (lp >> 2), X = bX + (lp & 3);
    int ivx = k >> 1, ivy = k & 1;    // branch order: (vx,vy) = (-,-),(-,+),(+,-),(+,+)
    int validY, iy; float relY;
    if (ivx == 0){ validY = (Y >= 1);   iy = (Y-1) >> 1; relY = (Y & 1) ?  0.5f :  1.5f; }
    else         { validY = (Y <= 254); iy = (Y+1) >> 1; relY = (Y & 1) ? -1.5f : -0.5f; }
    int validX, ix; float relX;
    if (ivy == 0){ validX = (X >= 1);   ix = (X-1) >> 1; relX = (X & 1) ?  0.5f :  1.5f; }
    else         { validX = (X <= 254); ix = (X+1) >> 1; relX = (X & 1) ? -1.5f : -0.5f; }
    int valid = validY && validX;     // joint: either axis OOB -> zero sample
    int spos = valid ? (iy*128 + ix) : -1;
    if (!valid){ relY = (float)Y + 0.5f - 128.0f; relX = (float)X + 0.5f - 128.0f; }
    rowpos[r] = spos; rowrely[r] = relY; rowrelx[r] = relX;
    int bpos = (Y >> 1)*128 + (X >> 1);
    float gc = 0.0f;
    if (valid){
      #pragma unroll
      for (int cc=0; cc<3; cc++){     // featc channels 252..254 = feat 124..126
        float fb = feat[(size_t)(124+cc)*16384 + bpos];
        float fq = feat[(size_t)(124+cc)*16384 + spos];
        gc += fb * fq;
      }
    }
    gcs[r] = gc;
  }
  __syncthreads();
  if (t < 16){
    float g0 = gcs[t*4+0], g1 = gcs[t*4+1], g2 = gcs[t*4+2], g3 = gcs[t*4+3];
    float mx = fmaxf(fmaxf(g0,g1), fmaxf(g2,g3));
    float e0 = __expf(g0-mx), e1 = __expf(g1-mx), e2 = __expf(g2-mx), e3 = __expf(g3-mx);
    float inv = 1.0f/(e0+e1+e2+e3);
    wgt[t*4+0]=e0*inv; wgt[t*4+1]=e1*inv; wgt[t*4+2]=e2*inv; wgt[t*4+3]=e3*inv;
  }

  // ---- step B: assemble h1 tile into LDS (bf16). thread t: row t>>2, 64 cols.
  {
    int m  = t >> 2;
    int cq = (t & 3) * 64;
    int lp = m >> 2;
    int Y = bY + (lp >> 2), X = bX + (lp & 3);
    size_t p = (size_t)Y*256 + X;
    int   spos = rowpos[m];
    float rely = rowrely[m], relx = rowrelx[m];
    const ushort* Gp   = G + p*256;
    const float*  w1r0 = W1 + 384*256;
    const float*  w1r1 = W1 + 385*256;
    #pragma unroll
    for (int jj=0; jj<8; jj++){
      int c = cq + jj*8;
      union { uint4 v; ushort s[8]; } gu, uu, ov;
      gu.v = *(const uint4*)(Gp + c);
      uu.v = make_uint4(0u,0u,0u,0u);
      if (spos >= 0) uu.v = *(const uint4*)(U + (size_t)spos*256 + c);
      float r0[8], r1[8];
      *(float4*)&r0[0] = *(const float4*)(w1r0 + c);
      *(float4*)&r0[4] = *(const float4*)(w1r0 + c + 4);
      *(float4*)&r1[0] = *(const float4*)(w1r1 + c);
      *(float4*)&r1[4] = *(const float4*)(w1r1 + c + 4);
      #pragma unroll
      for (int i=0; i<8; i++){
        float h = bf2f(uu.s[i]) + bf2f(gu.s[i]) + rely*r0[i] + relx*r1[i];
        ov.s[i] = f2bf(fmaxf(h, 0.0f));
      }
      *(uint4*)(&A1[m*264 + c]) = ov.v;
    }
  }
  __syncthreads();

  // ---- layer 2: [64 x 256] @ W2 [256 x 128]; wave owns 32 N-cols
  bf16x8 b2f[8][2];
  #pragma unroll
  for (int kt=0; kt<8; kt++)
    #pragma unroll
    for (int nt=0; nt<2; nt++)
      b2f[kt][nt] = ld8(&W2t[(size_t)(w*32 + nt*16 + l15)*256 + kt*32 + quad*8]);

  f32x4 acc2[4][2];
  #pragma unroll
  for (int mt=0; mt<4; mt++)
    #pragma unroll
    for (int nt=0; nt<2; nt++) acc2[mt][nt] = f32x4{0.f,0.f,0.f,0.f};

  #pragma unroll
  for (int mt=0; mt<4; mt++)
    #pragma unroll
    for (int kt=0; kt<8; kt++){
      bf16x8 a = ld8(&A1[(mt*16 + l15)*264 + kt*32 + quad*8]);
      #pragma unroll
      for (int nt=0; nt<2; nt++)
        acc2[mt][nt] = __builtin_amdgcn_mfma_f32_16x16x32_bf16(a, b2f[kt][nt], acc2[mt][nt], 0,0,0);
    }

  // h2 = relu(acc2 + b2) -> LDS
  {
    float bias0 = b2v[w*32 + l15], bias1 = b2v[w*32 + 16 + l15];
    #pragma unroll
    for (int mt=0; mt<4; mt++)
      #pragma unroll
      for (int nt=0; nt<2; nt++){
        int n = w*32 + nt*16 + l15;
        float bv = nt ? bias1 : bias0;
        #pragma unroll
        for (int r=0; r<4; r++){
          int m = mt*16 + quad*4 + r;
          A2[m*136 + n] = f2bf(fmaxf(acc2[mt][nt][r] + bv, 0.0f));
        }
      }
  }
  __syncthreads();

  // ---- layer 3: [64 x 128] @ W3 [128 x 32]; wave owns M-tile w
  bf16x8 b3f[4][2];
  #pragma unroll
  for (int kt=0; kt<4; kt++)
    #pragma unroll
    for (int nt=0; nt<2; nt++)
      b3f[kt][nt] = ld8(&W3t[(size_t)(nt*16 + l15)*128 + kt*32 + quad*8]);

  f32x4 acc3[2] = { f32x4{0.f,0.f,0.f,0.f}, f32x4{0.f,0.f,0.f,0.f} };
  #pragma unroll
  for (int kt=0; kt<4; kt++){
    bf16x8 a = ld8(&A2[(w*16 + l15)*136 + kt*32 + quad*8]);
    #pragma unroll
    for (int nt=0; nt<2; nt++)
      acc3[nt] = __builtin_amdgcn_mfma_f32_16x16x32_bf16(a, b3f[kt][nt], acc3[nt], 0,0,0);
  }

  // ---- epilogue: rows m = w*16 + quad*4 + r -> pixel lp = w*4+quad, branch r
  {
    int lp = w*4 + quad;
    int Y = bY + (lp >> 2), X = bX + (lp & 3);
    float w0 = wgt[lp*4+0], w1 = wgt[lp*4+1], w2 = wgt[lp*4+2], w3 = wgt[lp*4+3];
    #pragma unroll
    for (int nt=0; nt<2; nt++){
      int n = nt*16 + l15;
      float bb = b3v[n];
      float v = w0*(acc3[nt][0]+bb) + w1*(acc3[nt][1]+bb)
              + w2*(acc3[nt][2]+bb) + w3*(acc3[nt][3]+bb);
      outp[(size_t)n*65536 + (size_t)Y*256 + X] = v;
    }
  }
}

extern "C" void kernel_launch(void* const* d_in, const int* in_sizes, int n_in,
                              void* d_out, int out_size, void* d_ws, size_t ws_size,
                              hipStream_t stream)
{
  const float* feat     = (const float*)d_in[0];
  const float* lr_guide = (const float*)d_in[1];
  const float* hr_guide = (const float*)d_in[2];
  const float* W1       = (const float*)d_in[3];
  const float* b1       = (const float*)d_in[4];
  const float* W2       = (const float*)d_in[5];
  const float* b2       = (const float*)d_in[6];
  const float* W3       = (const float*)d_in[7];
  const float* b3       = (const float*)d_in[8];
  float* outp = (float*)d_out;

  char* ws = (char*)d_ws;
  ushort* W1t = (ushort*)(ws);                         // 98304 el = 196608 B
  ushort* W2t = (ushort*)(ws + 196608);                // 32768 el = 65536 B
  ushort* W3t = (ushort*)(ws + 196608 + 65536);        // 4096 el = 8192 B
  ushort* Ub  = (ushort*)(ws + 196608 + 65536 + 8192);            // 16384*256 = 8388608 B
  ushort* Gb  = (ushort*)(ws + 196608 + 65536 + 8192 + 8388608);  // 65536*256 = 33554432 B

  convert_weights<<<384, 256, 0, stream>>>(W1, W2, W3, W1t, W2t, W3t);
  // U: featc = [lr_guide; feat] (two K-halves), W1 rows 0..255
  stage1_gemm<<<256, 256, 0, stream>>>(lr_guide, feat, 16384, W1t, 0, nullptr, Ub);
  // G: hr_guide, W1 rows 256..383, + b1
  stage1_gemm<<<1024, 256, 0, stream>>>(hr_guide, nullptr, 65536, W1t, 256, b1, Gb);
  main_kernel<<<4096, 256, 0, stream>>>(feat, W1, b2, b3, Ub, Gb, W2t, W3t, outp);
}

// Round 2
// 204.122 us; speedup vs baseline: 1.4220x; 1.4220x over previous
//
#include <hip/hip_runtime.h>
#include <hip/hip_bf16.h>

// ---------------------------------------------------------------------------
// BF_NIR_conv, round 2: G fused into main kernel.
//   U[pos][256]  = featc[:,pos] @ W1[0:256,:]           (precomputed, 16384 LR)
//   per block (1x16 pixel row tile):
//     G[pix][256] = hr_guide[:,p] @ W1[256:384,:] + b1   (MFMA, in-LDS)
//     h1 = relu(U[spos] + G + rel_y*W1[384] + rel_x*W1[385])   (64 rows x 256)
//     h2 = relu(h1 @ W2 + b2);  pred = h2 @ W3 + b3
//     out = softmax(gc)-weighted sum over 4 branches
// ---------------------------------------------------------------------------

using bf16x8 = __attribute__((ext_vector_type(8))) __bf16;
using f32x4  = __attribute__((ext_vector_type(4))) float;

__device__ __forceinline__ float bf2f(unsigned short u){
  unsigned int x = ((unsigned int)u) << 16;
  return __builtin_bit_cast(float, x);
}
__device__ __forceinline__ unsigned short f2bf(float f){
  unsigned int x = __builtin_bit_cast(unsigned int, f);
  unsigned int r = x + 0x7fffu + ((x >> 16) & 1u);
  return (unsigned short)(r >> 16);
}
__device__ __forceinline__ bf16x8 ld8(const ushort* p){
  uint4 r = *(const uint4*)p;
  return __builtin_bit_cast(bf16x8, r);
}

struct RowMeta { int spos; float relY, relX; };
__device__ __forceinline__ RowMeta row_meta(int Y, int X, int br){
  int ivx = br >> 1, ivy = br & 1;   // branch order: (vx,vy)=(-,-),(-,+),(+,-),(+,+)
  int validY, iy; float relY;
  if (ivx == 0){ validY = (Y >= 1);   iy = (Y-1) >> 1; relY = (Y & 1) ?  0.5f :  1.5f; }
  else         { validY = (Y <= 254); iy = (Y+1) >> 1; relY = (Y & 1) ? -1.5f : -0.5f; }
  int validX, ix; float relX;
  if (ivy == 0){ validX = (X >= 1);   ix = (X-1) >> 1; relX = (X & 1) ?  0.5f :  1.5f; }
  else         { validX = (X <= 254); ix = (X+1) >> 1; relX = (X & 1) ? -1.5f : -0.5f; }
  RowMeta r;
  if (validY && validX){ r.spos = iy*128 + ix; r.relY = relY; r.relX = relX; }
  else { r.spos = -1; r.relY = (float)Y + 0.5f - 128.0f; r.relX = (float)X + 0.5f - 128.0f; }
  return r;
}

// --- kernel 0: convert weights to bf16, transposed to [N][K] -----------------
__global__ __launch_bounds__(256) void convert_weights(
    const float* __restrict__ W1, const float* __restrict__ W2,
    const float* __restrict__ W3,
    ushort* __restrict__ W1t,   // [256][384]
    ushort* __restrict__ W2t,   // [128][256]
    ushort* __restrict__ W3t)   // [32][128]
{
  int i = blockIdx.x*256 + threadIdx.x;           // grid = 384 blocks -> i < 98304
  { int k = i >> 8, n = i & 255; W1t[n*384 + k] = f2bf(W1[i]); }
  if (i < 32768){ int k = i >> 7, n = i & 127; W2t[n*256 + k] = f2bf(W2[i]); }
  if (i < 4096) { int k = i >> 5, n = i & 31;  W3t[n*128 + k] = f2bf(W3[i]); }
}

// --- kernel 1: U GEMM: out[pos][n] = sum_k [lr_guide;feat][k][pos]*W1[k][n] --
__global__ __launch_bounds__(256) void stage1_gemm(
    const float* __restrict__ src0, const float* __restrict__ src1, int M,
    const ushort* __restrict__ Bt, int koff,
    const float* __restrict__ bias,
    ushort* __restrict__ outp)                 // [M][256]
{
  __shared__ ushort A[64*136];
  const int t = threadIdx.x;
  const int w = t >> 6, lane = t & 63, quad = lane >> 4, l15 = lane & 15;
  const int pos0 = blockIdx.x * 64;
  const int nhalf = src1 ? 2 : 1;

  f32x4 acc[4][4];
  #pragma unroll
  for (int mt=0; mt<4; mt++)
    #pragma unroll
    for (int nt=0; nt<4; nt++) acc[mt][nt] = f32x4{0.f,0.f,0.f,0.f};

  for (int h=0; h<nhalf; h++){
    const float* src = h ? src1 : src0;
    #pragma unroll
    for (int i=0; i<32; i++){
      int f = i*256 + t;
      int k = f >> 6, mm = f & 63;
      A[mm*136 + k] = f2bf(src[(size_t)k*M + pos0 + mm]);
    }
    __syncthreads();
    bf16x8 b[4][4];
    #pragma unroll
    for (int kt=0; kt<4; kt++)
      #pragma unroll
      for (int nt=0; nt<4; nt++)
        b[kt][nt] = ld8(&Bt[(size_t)(w*64 + nt*16 + l15)*384 + koff + h*128 + kt*32 + quad*8]);
    #pragma unroll
    for (int mt=0; mt<4; mt++)
      #pragma unroll
      for (int kt=0; kt<4; kt++){
        bf16x8 a = ld8(&A[(mt*16 + l15)*136 + kt*32 + quad*8]);
        #pragma unroll
        for (int nt=0; nt<4; nt++)
          acc[mt][nt] = __builtin_amdgcn_mfma_f32_16x16x32_bf16(a, b[kt][nt], acc[mt][nt], 0,0,0);
      }
    __syncthreads();
  }
  #pragma unroll
  for (int mt=0; mt<4; mt++)
    #pragma unroll
    for (int nt=0; nt<4; nt++){
      int n = w*64 + nt*16 + l15;
      float bv = bias ? bias[n] : 0.0f;
      #pragma unroll
      for (int r=0; r<4; r++){
        int mm = mt*16 + quad*4 + r;
        outp[(size_t)(pos0 + mm)*256 + n] = f2bf(acc[mt][nt][r] + bv);
      }
    }
}

// --- kernel 2: fused main. Block = 16 pixels (1x16 row) x 4 branches = 64 rows.
__global__ __launch_bounds__(256, 3) void main_fused(
    const float* __restrict__ feat,      // [128][16384]
    const float* __restrict__ hr_guide,  // [128][65536]
    const float* __restrict__ W1,        // [386][256] fp32 (rel rows 384/385)
    const float* __restrict__ b1v,
    const float* __restrict__ b2v,
    const float* __restrict__ b3v,
    const ushort* __restrict__ U,        // [16384][256] bf16
    const ushort* __restrict__ W1t,      // [256][384] bf16 (N-major)
    const ushort* __restrict__ W2t,      // [128][256] bf16 (N-major)
    const ushort* __restrict__ W3t,      // [32][128]  bf16 (N-major)
    float* __restrict__ outp)            // [32][65536]
{
  // LDS: A1 (h1 64x256, stride 264) with hr-stage (16x128, stride 136) aliased
  // at its base and h2 (64x128, stride 136) aliased after sync4; Gt 16x256
  // (stride 264); w1 rel rows fp32; gcs/wgt.  Total ~44.8 KB -> 3 blocks/CU.
  __shared__ __align__(16) ushort A1[64*264];
  __shared__ __align__(16) ushort Gt[16*264];
  __shared__ __align__(16) float  w1r[2][256];
  __shared__ float gcs[64];
  __shared__ float wgt[64];

  const int t = threadIdx.x;
  const int w = t >> 6, lane = t & 63, quad = lane >> 4, l15 = lane & 15;
  const int Y  = blockIdx.x >> 4;
  const int X0 = (blockIdx.x & 15) << 4;

  // ---- phase 0: metadata in registers, U preload, hr staging, w1r, gc ----
  const int m   = t >> 2;            // h1 row handled by this thread
  const int pix = m >> 2, br = m & 3;
  const int c0  = (t & 3) * 64;
  RowMeta rm = row_meta(Y, X0 + pix, br);

  uint4 uu[8];
  if (rm.spos >= 0){
    const ushort* Up = U + (size_t)rm.spos*256 + c0;
    #pragma unroll
    for (int j=0; j<8; j++) uu[j] = *(const uint4*)(Up + j*8);
  } else {
    #pragma unroll
    for (int j=0; j<8; j++) uu[j] = make_uint4(0u,0u,0u,0u);
  }

  {
    ushort* Ahr = A1;                // alias: [pix][ch], stride 136
    #pragma unroll
    for (int i=0; i<2; i++){
      int id = i*256 + t;            // 0..511
      int ch = id >> 2, xq = id & 3;
      float4 v = *(const float4*)(hr_guide + (size_t)ch*65536 + Y*256 + X0 + xq*4);
      Ahr[(xq*4+0)*136 + ch] = f2bf(v.x);
      Ahr[(xq*4+1)*136 + ch] = f2bf(v.y);
      Ahr[(xq*4+2)*136 + ch] = f2bf(v.z);
      Ahr[(xq*4+3)*136 + ch] = f2bf(v.w);
    }
  }
  w1r[0][t] = W1[384*256 + t];
  w1r[1][t] = W1[385*256 + t];

  if (t < 64){
    RowMeta g = row_meta(Y, X0 + (t>>2), t & 3);
    float gc = 0.0f;
    if (g.spos >= 0){
      int bpos = (Y>>1)*128 + ((X0 + (t>>2)) >> 1);
      #pragma unroll
      for (int cc=0; cc<3; cc++)
        gc += feat[(size_t)(124+cc)*16384 + bpos] * feat[(size_t)(124+cc)*16384 + g.spos];
    }
    gcs[t] = gc;
  }
  __syncthreads();                                   // sync1

  // ---- phase 1: softmax weights + G MFMA (M=16 pix, N=256, K=128) ----
  if (t < 16){
    float g0 = gcs[t*4+0], g1 = gcs[t*4+1], g2 = gcs[t*4+2], g3 = gcs[t*4+3];
    float mx = fmaxf(fmaxf(g0,g1), fmaxf(g2,g3));
    float e0 = __expf(g0-mx), e1 = __expf(g1-mx), e2 = __expf(g2-mx), e3 = __expf(g3-mx);
    float inv = 1.0f/(e0+e1+e2+e3);
    wgt[t*4+0]=e0*inv; wgt[t*4+1]=e1*inv; wgt[t*4+2]=e2*inv; wgt[t*4+3]=e3*inv;
  }
  {
    f32x4 accg[4];
    #pragma unroll
    for (int nt=0; nt<4; nt++) accg[nt] = f32x4{0.f,0.f,0.f,0.f};
    #pragma unroll
    for (int kt=0; kt<4; kt++){
      bf16x8 a = ld8(&A1[l15*136 + kt*32 + quad*8]);           // Ahr alias
      #pragma unroll
      for (int nt=0; nt<4; nt++){
        bf16x8 b = ld8(&W1t[(size_t)(w*64 + nt*16 + l15)*384 + 256 + kt*32 + quad*8]);
        accg[nt] = __builtin_amdgcn_mfma_f32_16x16x32_bf16(a, b, accg[nt], 0,0,0);
      }
    }
    #pragma unroll
    for (int nt=0; nt<4; nt++){
      int n = w*64 + nt*16 + l15;
      float bv = b1v[n];
      #pragma unroll
      for (int r=0; r<4; r++)
        Gt[(quad*4+r)*264 + n] = f2bf(accg[nt][r] + bv);       // C/D: row=quad*4+r
    }
  }
  __syncthreads();                                   // sync2

  // ---- phase 2: W2 fragment preload + h1 assembly into A1 ----
  bf16x8 b2f[8][2];
  #pragma unroll
  for (int kt=0; kt<8; kt++)
    #pragma unroll
    for (int nt=0; nt<2; nt++)
      b2f[kt][nt] = ld8(&W2t[(size_t)(w*32 + nt*16 + l15)*256 + kt*32 + quad*8]);

  {
    float relY = rm.relY, relX = rm.relX;
    #pragma unroll
    for (int jj=0; jj<8; jj++){
      int c = c0 + jj*8;
      union { uint4 v; ushort s[8]; } gu, uv, ov;
      gu.v = *(const uint4*)&Gt[pix*264 + c];
      uv.v = uu[jj];
      float r0[8], r1[8];
      *(float4*)&r0[0] = *(const float4*)&w1r[0][c];
      *(float4*)&r0[4] = *(const float4*)&w1r[0][c+4];
      *(float4*)&r1[0] = *(const float4*)&w1r[1][c];
      *(float4*)&r1[4] = *(const float4*)&w1r[1][c+4];
      #pragma unroll
      for (int i=0; i<8; i++){
        float h = bf2f(uv.s[i]) + bf2f(gu.s[i]) + relY*r0[i] + relX*r1[i];
        ov.s[i] = f2bf(fmaxf(h, 0.0f));
      }
      *(uint4*)&A1[m*264 + c] = ov.v;
    }
  }
  __syncthreads();                                   // sync3

  // ---- phase 3: layer 2 [64x256] @ W2 [256x128]; wave owns 32 N-cols ----
  f32x4 acc2[4][2];
  #pragma unroll
  for (int mt=0; mt<4; mt++)
    #pragma unroll
    for (int nt=0; nt<2; nt++) acc2[mt][nt] = f32x4{0.f,0.f,0.f,0.f};
  #pragma unroll
  for (int mt=0; mt<4; mt++)
    #pragma unroll
    for (int kt=0; kt<8; kt++){
      bf16x8 a = ld8(&A1[(mt*16 + l15)*264 + kt*32 + quad*8]);
      #pragma unroll
      for (int nt=0; nt<2; nt++)
        acc2[mt][nt] = __builtin_amdgcn_mfma_f32_16x16x32_bf16(a, b2f[kt][nt], acc2[mt][nt], 0,0,0);
    }
  __syncthreads();                                   // sync4 (A1 reads done)

  // ---- phase 4: W3 preload, h2 -> A2 (aliases A1, stride 136) ----
  bf16x8 b3f[4][2];
  #pragma unroll
  for (int kt=0; kt<4; kt++)
    #pragma unroll
    for (int nt=0; nt<2; nt++)
      b3f[kt][nt] = ld8(&W3t[(size_t)(nt*16 + l15)*128 + kt*32 + quad*8]);

  {
    ushort* A2 = A1;
    float bias0 = b2v[w*32 + l15], bias1 = b2v[w*32 + 16 + l15];
    #pragma unroll
    for (int mt=0; mt<4; mt++)
      #pragma unroll
      for (int nt=0; nt<2; nt++){
        int n = w*32 + nt*16 + l15;
        float bv = nt ? bias1 : bias0;
        #pragma unroll
        for (int r=0; r<4; r++){
          int mm = mt*16 + quad*4 + r;
          A2[mm*136 + n] = f2bf(fmaxf(acc2[mt][nt][r] + bv, 0.0f));
        }
      }
  }
  __syncthreads();                                   // sync5

  // ---- phase 5: layer 3 [64x128] @ W3 [128x32]; wave owns M-tile w ----
  {
    const ushort* A2 = A1;
    f32x4 acc3[2] = { f32x4{0.f,0.f,0.f,0.f}, f32x4{0.f,0.f,0.f,0.f} };
    #pragma unroll
    for (int kt=0; kt<4; kt++){
      bf16x8 a = ld8(&A2[(w*16 + l15)*136 + kt*32 + quad*8]);
      #pragma unroll
      for (int nt=0; nt<2; nt++)
        acc3[nt] = __builtin_amdgcn_mfma_f32_16x16x32_bf16(a, b3f[kt][nt], acc3[nt], 0,0,0);
    }
    // epilogue: row = w*16+quad*4+r -> pixel lp=w*4+quad, branch r
    int lp = w*4 + quad;
    int X = X0 + lp;
    float w0 = wgt[lp*4+0], w1 = wgt[lp*4+1], w2 = wgt[lp*4+2], w3 = wgt[lp*4+3];
    #pragma unroll
    for (int nt=0; nt<2; nt++){
      int n = nt*16 + l15;
      float bb = b3v[n];
      float v = w0*(acc3[nt][0]+bb) + w1*(acc3[nt][1]+bb)
              + w2*(acc3[nt][2]+bb) + w3*(acc3[nt][3]+bb);
      outp[(size_t)n*65536 + (size_t)Y*256 + X] = v;
    }
  }
}

extern "C" void kernel_launch(void* const* d_in, const int* in_sizes, int n_in,
                              void* d_out, int out_size, void* d_ws, size_t ws_size,
                              hipStream_t stream)
{
  const float* feat     = (const float*)d_in[0];
  const float* lr_guide = (const float*)d_in[1];
  const float* hr_guide = (const float*)d_in[2];
  const float* W1       = (const float*)d_in[3];
  const float* b1       = (const float*)d_in[4];
  const float* W2       = (const float*)d_in[5];
  const float* b2       = (const float*)d_in[6];
  const float* W3       = (const float*)d_in[7];
  const float* b3       = (const float*)d_in[8];
  float* outp = (float*)d_out;

  char* ws = (char*)d_ws;
  ushort* W1t = (ushort*)(ws);                         // 98304 el = 196608 B
  ushort* W2t = (ushort*)(ws + 196608);                // 32768 el = 65536 B
  ushort* W3t = (ushort*)(ws + 196608 + 65536);        // 4096 el = 8192 B
  ushort* Ub  = (ushort*)(ws + 196608 + 65536 + 8192); // 16384*256*2 = 8388608 B

  convert_weights<<<384, 256, 0, stream>>>(W1, W2, W3, W1t, W2t, W3t);
  // U: featc = [lr_guide; feat] (two K-halves), W1 rows 0..255
  stage1_gemm<<<256, 256, 0, stream>>>(lr_guide, feat, 16384, W1t, 0, nullptr, Ub);
  // fused G + MLP + softmax-combine
  main_fused<<<4096, 256, 0, stream>>>(feat, hr_guide, W1, b1, b2, b3,
                                       Ub, W1t, W2t, W3t, outp);
}